// Round 1
// baseline (348.973 us; speedup 1.0000x reference)
//
#include <hip/hip_runtime.h>
#include <stdint.h>

#define M_DIM 8192
#define N_DIM 4096
#define K_DIM 4224
#define BK 64

typedef float f32x16 __attribute__((ext_vector_type(16)));
typedef int   i32x8  __attribute__((ext_vector_type(8)));
typedef int   i32x4  __attribute__((ext_vector_type(4)));

#define RAW_BARRIER()  asm volatile("s_barrier" ::: "memory")
#define WAIT_VM0()     asm volatile("s_waitcnt vmcnt(0)" ::: "memory")

// ---------------------------------------------------------------------------
// fp4(e2m1) nibble + per-16 E8M0 scale -> exact bf8(e5m2), pure VALU.
// base byte for mag m in {0..7}: {0x00,0x38,0x3C,0x3E,0x40,0x42,0x44,0x46}
// scale fold: byte += s4 (= (sf-127)<<2) iff m!=0; exp field stays in [5,23].
// Packed-carry-safe form: base + nz*(s4+64) - nz*64 per byte (range [0x14,0x9E]).
// ---------------------------------------------------------------------------
__device__ __forceinline__ uint32_t conv4(uint32_t x, uint32_t k1) {
    uint32_t n7   = x & 0x07070707u;
    uint32_t base = __builtin_amdgcn_perm(0x46444240u, 0x3E3C3800u, n7);
    uint32_t nz   = __builtin_amdgcn_perm(0x01010101u, 0x01010100u, n7);
    uint32_t sign = (x & 0x08080808u) << 4;
    return (base + nz * k1 - (nz << 6)) | sign;
}

__global__ __launch_bounds__(256) void dequant_all(
    const int* __restrict__ Ap, const int* __restrict__ SFA, uint8_t* __restrict__ Aout,
    const int* __restrict__ Bp, const int* __restrict__ SFB, uint8_t* __restrict__ Bout)
{
    const int nblkA = M_DIM * K_DIM / 16;
    int i = blockIdx.x * 256 + threadIdx.x;
    const int* p; const int* sf; uint8_t* out; int idx;
    if (i < nblkA) { p = Ap; sf = SFA; out = Aout; idx = i; }
    else           { p = Bp; sf = SFB; out = Bout; idx = i - nblkA; }

    const int4* p4 = (const int4*)p;
    int4 p0 = p4[2 * idx];
    int4 p1 = p4[2 * idx + 1];
    int s4 = (sf[idx] - 127) << 2;
    uint32_t k1 = (uint32_t)(s4 + 64);

    uint32_t o[4];
#pragma unroll
    for (int g = 0; g < 2; ++g) {
        int4 pg = g ? p1 : p0;
        uint32_t w = (uint32_t)(pg.x & 0xFF) | ((uint32_t)(pg.y & 0xFF) << 8) |
                     ((uint32_t)(pg.z & 0xFF) << 16) | ((uint32_t)pg.w << 24);
        uint32_t lr = conv4(w & 0x0F0F0F0Fu, k1);
        uint32_t hr = conv4((w >> 4) & 0x0F0F0F0Fu, k1);
        o[2 * g]     = __builtin_amdgcn_perm(hr, lr, 0x05010400u); // elems 0..3
        o[2 * g + 1] = __builtin_amdgcn_perm(hr, lr, 0x07030602u); // elems 4..7
    }
    *(uint4*)(out + (size_t)idx * 16) = make_uint4(o[0], o[1], o[2], o[3]);
}

// ---------------------------------------------------------------------------
// GEMM via MX-scaled MFMA at unity scale: C = scale*(A.B^T) + bias
// 256x256 tile, 8 waves (2Mx4N), BK=64, bf8 operands.
// - LDS: 2 buffers x (A 16KB + B 16KB) = 64 KB exactly.
// - T3 minimum-2-phase loop: STAGE(t+1, other buf) at top of compute(t),
//   one vmcnt(0)+s_barrier per tile -> loads hide under full compute phase.
// - XOR-swizzled LDS granules (granule g of row r lives at slot g^((r>>1)&3)):
//   conflict-free ds_read_b128 fragment reads; staging stays lane-linear.
// - T1: XCD-aware bijective block swizzle (512 blocks, 64/XCD chunk).
// - T5: setprio(1) around the 8-MFMA cluster.
// ---------------------------------------------------------------------------
__global__ __launch_bounds__(512, 2) void gemm_mx(
    const uint8_t* __restrict__ A, const uint8_t* __restrict__ B,
    const float* __restrict__ scale, const float* __restrict__ bias,
    float* __restrict__ C)
{
    __shared__ uint8_t smem[65536];
    // buf0: A [256][64] at 0, B [256][64] at 16384; buf1 at +32768

    const int tid  = threadIdx.x;
    const int lane = tid & 63;
    const int w    = tid >> 6;      // 0..7
    const int wm   = w >> 2;        // 0..1 : 128-row band
    const int wn   = w & 3;         // 0..3 : 64-col band
    const int r31  = lane & 31;
    const int h    = lane >> 5;

    // XCD-aware swizzle: 512 blocks total, chunk of 64 consecutive per XCD
    const int lin = blockIdx.y * 16 + blockIdx.x;        // gridDim.x == 16
    const int o   = (lin & 7) * 64 + (lin >> 3);         // bijective (512 % 8 == 0)
    const int bn0 = (o & 15) * 256;
    const int bm0 = (o >> 4) * 256;

    f32x16 acc[4][2];
#pragma unroll
    for (int i = 0; i < 4; ++i)
#pragma unroll
        for (int j = 0; j < 2; ++j)
            acc[i][j] = (f32x16)(0.0f);

    // staging: wave w stages rows [w*32, w*32+32) of A and of B,
    // 2 issues of 16 rows x 64B per matrix (4 global_load_lds per wave per tile).
    // lane slot = local_row*4 + g''; fetch global granule g = g'' ^ ((row>>1)&3)
    const int srow = lane >> 2;
    const int scol = (((lane & 3) ^ ((lane >> 3) & 3)) << 4);
    const uint8_t* Ag = A + (size_t)(bm0 + w * 32 + srow) * K_DIM + scol;
    const uint8_t* Bg = B + (size_t)(bn0 + w * 32 + srow) * K_DIM + scol;
    uint8_t* Asw = smem + w * 2048;
    uint8_t* Bsw = smem + 16384 + w * 2048;

#define STAGE(koff, boff)                                                        \
    do {                                                                         \
        const uint8_t* ag_ = Ag + (koff);                                        \
        const uint8_t* bg_ = Bg + (koff);                                        \
        __builtin_amdgcn_global_load_lds(                                        \
            (const __attribute__((address_space(1))) void*)(ag_),                \
            (__attribute__((address_space(3))) void*)(Asw + (boff)), 16, 0, 0);  \
        __builtin_amdgcn_global_load_lds(                                        \
            (const __attribute__((address_space(1))) void*)(ag_ + (size_t)16 * K_DIM), \
            (__attribute__((address_space(3))) void*)(Asw + (boff) + 1024), 16, 0, 0); \
        __builtin_amdgcn_global_load_lds(                                        \
            (const __attribute__((address_space(1))) void*)(bg_),                \
            (__attribute__((address_space(3))) void*)(Bsw + (boff)), 16, 0, 0);  \
        __builtin_amdgcn_global_load_lds(                                        \
            (const __attribute__((address_space(1))) void*)(bg_ + (size_t)16 * K_DIM), \
            (__attribute__((address_space(3))) void*)(Bsw + (boff) + 1024), 16, 0, 0); \
    } while (0)

    // swizzled, kt-invariant fragment addresses (buf0; buf1 = +32768)
    const int sx = (r31 >> 1) & 3;
    const uint8_t* pa_lo[4]; const uint8_t* pa_hi[4];
    const uint8_t* pb_lo[2]; const uint8_t* pb_hi[2];
#pragma unroll
    for (int mi = 0; mi < 4; ++mi) {
        const uint8_t* base = smem + (wm * 128 + mi * 32 + r31) * 64;
        pa_lo[mi] = base + (((2 * h)     ^ sx) << 4);
        pa_hi[mi] = base + (((2 * h + 1) ^ sx) << 4);
    }
#pragma unroll
    for (int ni = 0; ni < 2; ++ni) {
        const uint8_t* base = smem + 16384 + (wn * 64 + ni * 32 + r31) * 64;
        pb_lo[ni] = base + (((2 * h)     ^ sx) << 4);
        pb_hi[ni] = base + (((2 * h + 1) ^ sx) << 4);
    }

    auto compute = [&](int off) {
        i32x8 af[4], bf[2];
#pragma unroll
        for (int mi = 0; mi < 4; ++mi) {
            i32x4 lo = *(const i32x4*)(pa_lo[mi] + off);
            i32x4 hi = *(const i32x4*)(pa_hi[mi] + off);
            af[mi] = __builtin_shufflevector(lo, hi, 0, 1, 2, 3, 4, 5, 6, 7);
        }
#pragma unroll
        for (int ni = 0; ni < 2; ++ni) {
            i32x4 lo = *(const i32x4*)(pb_lo[ni] + off);
            i32x4 hi = *(const i32x4*)(pb_hi[ni] + off);
            bf[ni] = __builtin_shufflevector(lo, hi, 0, 1, 2, 3, 4, 5, 6, 7);
        }
        __builtin_amdgcn_s_setprio(1);
#pragma unroll
        for (int mi = 0; mi < 4; ++mi)
#pragma unroll
            for (int ni = 0; ni < 2; ++ni)
                acc[mi][ni] = __builtin_amdgcn_mfma_scale_f32_32x32x64_f8f6f4(
                    af[mi], bf[ni], acc[mi][ni],
                    1, 1,                 // cbsz=bf8(e5m2), blgp=bf8(e5m2)
                    0, 0x7F7F7F7F,        // scale A = 2^0
                    0, 0x7F7F7F7F);       // scale B = 2^0
        __builtin_amdgcn_s_setprio(0);
    };

    const int NT = K_DIM / BK;   // 66 (even)
    (void)NT;

    // prologue: tile 0 -> buf0
    STAGE(0, 0);
    WAIT_VM0();
    RAW_BARRIER();

    for (int kt = 0; kt < 64; kt += 2) {
        // tile kt in buf0; prefetch kt+1 -> buf1 (hides under this compute)
        STAGE((kt + 1) * BK, 32768);
        compute(0);
        WAIT_VM0();          // own tile-(kt+1) loads done
        RAW_BARRIER();       // everyone's done; buf1 ready, buf0 free to overwrite

        // tile kt+1 in buf1; prefetch kt+2 -> buf0
        STAGE((kt + 2) * BK, 0);
        compute(32768);
        WAIT_VM0();
        RAW_BARRIER();
    }
    // tile 64 in buf0; prefetch 65 -> buf1
    STAGE(65 * BK, 32768);
    compute(0);
    WAIT_VM0();
    RAW_BARRIER();
    // tile 65 in buf1 (no prefetch)
    compute(32768);
#undef STAGE

    const float sc = scale[0];
#pragma unroll
    for (int ni = 0; ni < 2; ++ni) {
        const int col = bn0 + wn * 64 + ni * 32 + r31;
        const float bv = bias[col];
#pragma unroll
        for (int mi = 0; mi < 4; ++mi) {
            const int rbase = bm0 + wm * 128 + mi * 32 + 4 * h;
#pragma unroll
            for (int reg = 0; reg < 16; ++reg) {
                const int row = rbase + (reg & 3) + 8 * (reg >> 2);
                C[(size_t)row * N_DIM + col] = sc * acc[mi][ni][reg] + bv;
            }
        }
    }
}

extern "C" void kernel_launch(void* const* d_in, const int* in_sizes, int n_in,
                              void* d_out, int out_size, void* d_ws, size_t ws_size,
                              hipStream_t stream) {
    const int*   A_packed = (const int*)d_in[0];
    const int*   SFA      = (const int*)d_in[1];
    const float* scale    = (const float*)d_in[2];
    const int*   B_packed = (const int*)d_in[3];
    const int*   SFB      = (const int*)d_in[4];
    const float* bias     = (const float*)d_in[5];
    float*       out      = (float*)d_out;

    uint8_t* Abf8 = (uint8_t*)d_ws;
    uint8_t* Bbf8 = Abf8 + (size_t)M_DIM * K_DIM;

    const int nblkA = M_DIM * K_DIM / 16;   // 2,162,688 (8448 blocks of 256)
    const int nblkB = N_DIM * K_DIM / 16;   // 1,081,344 (4224 blocks)
    dequant_all<<<(nblkA + nblkB) / 256, 256, 0, stream>>>(
        A_packed, SFA, Abf8, B_packed, SFB, Bbf8);

    dim3 grid(N_DIM / 256, M_DIM / 256);    // (16, 32) = 512 blocks
    gemm_mx<<<grid, 512, 0, stream>>>(Abf8, Bbf8, scale, bias, out);
}

// Round 2
// 346.831 us; speedup vs baseline: 1.0062x; 1.0062x over previous
//
#include <hip/hip_runtime.h>
#include <stdint.h>

#define M_DIM 8192
#define N_DIM 4096
#define K_DIM 4224
#define BK 64

typedef float f32x16 __attribute__((ext_vector_type(16)));
typedef int   i32x8  __attribute__((ext_vector_type(8)));
typedef int   i32x4  __attribute__((ext_vector_type(4)));

#define RAW_BARRIER()  asm volatile("s_barrier" ::: "memory")
#define WAIT_VM4()     asm volatile("s_waitcnt vmcnt(4)" ::: "memory")
#define WAIT_VM0()     asm volatile("s_waitcnt vmcnt(0)" ::: "memory")

// ---------------------------------------------------------------------------
// fp4(e2m1) nibble + per-16 E8M0 scale -> exact bf8(e5m2), pure VALU.
// base byte for mag m in {0..7}: {0x00,0x38,0x3C,0x3E,0x40,0x42,0x44,0x46}
// scale fold: byte += s4 (= (sf-127)<<2) iff m!=0; exp field stays in [5,23].
// Packed-carry-safe form: base + nz*(s4+64) - nz*64 per byte (range [0x14,0x9E]).
// ---------------------------------------------------------------------------
__device__ __forceinline__ uint32_t conv4(uint32_t x, uint32_t k1) {
    uint32_t n7   = x & 0x07070707u;
    uint32_t base = __builtin_amdgcn_perm(0x46444240u, 0x3E3C3800u, n7);
    uint32_t nz   = __builtin_amdgcn_perm(0x01010101u, 0x01010100u, n7);
    uint32_t sign = (x & 0x08080808u) << 4;
    return (base + nz * k1 - (nz << 6)) | sign;
}

__global__ __launch_bounds__(256) void dequant_all(
    const int* __restrict__ Ap, const int* __restrict__ SFA, uint8_t* __restrict__ Aout,
    const int* __restrict__ Bp, const int* __restrict__ SFB, uint8_t* __restrict__ Bout)
{
    const int nblkA = M_DIM * K_DIM / 16;
    int i = blockIdx.x * 256 + threadIdx.x;
    const int* p; const int* sf; uint8_t* out; int idx;
    if (i < nblkA) { p = Ap; sf = SFA; out = Aout; idx = i; }
    else           { p = Bp; sf = SFB; out = Bout; idx = i - nblkA; }

    const int4* p4 = (const int4*)p;
    int4 p0 = p4[2 * idx];
    int4 p1 = p4[2 * idx + 1];
    int s4 = (sf[idx] - 127) << 2;
    uint32_t k1 = (uint32_t)(s4 + 64);

    uint32_t o[4];
#pragma unroll
    for (int g = 0; g < 2; ++g) {
        int4 pg = g ? p1 : p0;
        uint32_t w = (uint32_t)(pg.x & 0xFF) | ((uint32_t)(pg.y & 0xFF) << 8) |
                     ((uint32_t)(pg.z & 0xFF) << 16) | ((uint32_t)pg.w << 24);
        uint32_t lr = conv4(w & 0x0F0F0F0Fu, k1);
        uint32_t hr = conv4((w >> 4) & 0x0F0F0F0Fu, k1);
        o[2 * g]     = __builtin_amdgcn_perm(hr, lr, 0x05010400u); // elems 0..3
        o[2 * g + 1] = __builtin_amdgcn_perm(hr, lr, 0x07030602u); // elems 4..7
    }
    *(uint4*)(out + (size_t)idx * 16) = make_uint4(o[0], o[1], o[2], o[3]);
}

// ---------------------------------------------------------------------------
// GEMM via MX-scaled MFMA at unity scale: C = scale*(A.B^T) + bias
// 256x256 tile, 8 waves (2Mx4N), BK=64, bf8 operands.
// - LDS: 3 tile buffers x (A 16KB + B 16KB) = 96 KB -> prefetch depth 2.
// - Counted vmcnt(4) per tile, NEVER drained to 0 in steady state (T4):
//   tile t+1's 4 loads have a full iteration (~2700 cy) to land; tile t+2's
//   loads stay in flight across the barrier.
// - ONE barrier per tile: stage into buf X at iter t+1 is safe because X's
//   readers consumed their ds_reads via MFMA dataflow (lgkmcnt) before
//   arriving at iter t's barrier; read-after-stage gated by FIFO vmcnt.
// - XOR-swizzled LDS granules (granule g of row r at slot g^((r>>1)&3)):
//   conflict-free ds_read_b128 fragment reads; staging stays lane-linear.
// - T1: XCD-aware bijective block swizzle. T5: setprio around MFMA cluster.
// ---------------------------------------------------------------------------
__global__ __launch_bounds__(512, 2) void gemm_mx(
    const uint8_t* __restrict__ A, const uint8_t* __restrict__ B,
    const float* __restrict__ scale, const float* __restrict__ bias,
    float* __restrict__ C)
{
    __shared__ uint8_t smem[98304];
    // buf k at offset k*32768: A [256][64] at +0, B [256][64] at +16384

    const int tid  = threadIdx.x;
    const int lane = tid & 63;
    const int w    = tid >> 6;      // 0..7
    const int wm   = w >> 2;        // 0..1 : 128-row band
    const int wn   = w & 3;         // 0..3 : 64-col band
    const int r31  = lane & 31;
    const int h    = lane >> 5;

    // XCD-aware swizzle: 512 blocks total, chunk of 64 consecutive per XCD
    const int lin = blockIdx.y * 16 + blockIdx.x;        // gridDim.x == 16
    const int o   = (lin & 7) * 64 + (lin >> 3);         // bijective (512 % 8 == 0)
    const int bn0 = (o & 15) * 256;
    const int bm0 = (o >> 4) * 256;

    f32x16 acc[4][2];
#pragma unroll
    for (int i = 0; i < 4; ++i)
#pragma unroll
        for (int j = 0; j < 2; ++j)
            acc[i][j] = (f32x16)(0.0f);

    // staging: wave w stages rows [w*32, w*32+32) of A and of B,
    // 2 issues of 16 rows x 64B per matrix (4 global_load_lds per wave per tile).
    // lane slot = local_row*4 + g''; fetch global granule g = g'' ^ ((row>>1)&3)
    const int srow = lane >> 2;
    const int scol = (((lane & 3) ^ ((lane >> 3) & 3)) << 4);
    const uint8_t* Ag = A + (size_t)(bm0 + w * 32 + srow) * K_DIM + scol;
    const uint8_t* Bg = B + (size_t)(bn0 + w * 32 + srow) * K_DIM + scol;
    uint8_t* Asw = smem + w * 2048;
    uint8_t* Bsw = smem + 16384 + w * 2048;

#define STAGE(koff, boff)                                                        \
    do {                                                                         \
        const uint8_t* ag_ = Ag + (koff);                                        \
        const uint8_t* bg_ = Bg + (koff);                                        \
        __builtin_amdgcn_global_load_lds(                                        \
            (const __attribute__((address_space(1))) void*)(ag_),                \
            (__attribute__((address_space(3))) void*)(Asw + (boff)), 16, 0, 0);  \
        __builtin_amdgcn_global_load_lds(                                        \
            (const __attribute__((address_space(1))) void*)(ag_ + (size_t)16 * K_DIM), \
            (__attribute__((address_space(3))) void*)(Asw + (boff) + 1024), 16, 0, 0); \
        __builtin_amdgcn_global_load_lds(                                        \
            (const __attribute__((address_space(1))) void*)(bg_),                \
            (__attribute__((address_space(3))) void*)(Bsw + (boff)), 16, 0, 0);  \
        __builtin_amdgcn_global_load_lds(                                        \
            (const __attribute__((address_space(1))) void*)(bg_ + (size_t)16 * K_DIM), \
            (__attribute__((address_space(3))) void*)(Bsw + (boff) + 1024), 16, 0, 0); \
    } while (0)

    // swizzled, kt-invariant fragment addresses (buf0; bufk = +k*32768)
    const int sx = (r31 >> 1) & 3;
    const uint8_t* pa_lo[4]; const uint8_t* pa_hi[4];
    const uint8_t* pb_lo[2]; const uint8_t* pb_hi[2];
#pragma unroll
    for (int mi = 0; mi < 4; ++mi) {
        const uint8_t* base = smem + (wm * 128 + mi * 32 + r31) * 64;
        pa_lo[mi] = base + (((2 * h)     ^ sx) << 4);
        pa_hi[mi] = base + (((2 * h + 1) ^ sx) << 4);
    }
#pragma unroll
    for (int ni = 0; ni < 2; ++ni) {
        const uint8_t* base = smem + 16384 + (wn * 64 + ni * 32 + r31) * 64;
        pb_lo[ni] = base + (((2 * h)     ^ sx) << 4);
        pb_hi[ni] = base + (((2 * h + 1) ^ sx) << 4);
    }

    auto compute = [&](int off) {
        i32x8 af[4], bf[2];
#pragma unroll
        for (int mi = 0; mi < 4; ++mi) {
            i32x4 lo = *(const i32x4*)(pa_lo[mi] + off);
            i32x4 hi = *(const i32x4*)(pa_hi[mi] + off);
            af[mi] = __builtin_shufflevector(lo, hi, 0, 1, 2, 3, 4, 5, 6, 7);
        }
#pragma unroll
        for (int ni = 0; ni < 2; ++ni) {
            i32x4 lo = *(const i32x4*)(pb_lo[ni] + off);
            i32x4 hi = *(const i32x4*)(pb_hi[ni] + off);
            bf[ni] = __builtin_shufflevector(lo, hi, 0, 1, 2, 3, 4, 5, 6, 7);
        }
        __builtin_amdgcn_s_setprio(1);
#pragma unroll
        for (int mi = 0; mi < 4; ++mi)
#pragma unroll
            for (int ni = 0; ni < 2; ++ni)
                acc[mi][ni] = __builtin_amdgcn_mfma_scale_f32_32x32x64_f8f6f4(
                    af[mi], bf[ni], acc[mi][ni],
                    1, 1,                 // cbsz=bf8(e5m2), blgp=bf8(e5m2)
                    0, 0x7F7F7F7F,        // scale A = 2^0
                    0, 0x7F7F7F7F);       // scale B = 2^0
        __builtin_amdgcn_s_setprio(0);
    };

    // NT = 66 tiles. Buffers rotate t%3 (66 = 3*22, all offsets static).
    // Steady state: iter t stages tile t+2 -> buf[(t+2)%3], computes buf[t%3],
    // then vmcnt(4) (waits tile t+1's 4 loads; leaves t+2's in flight), barrier.
    STAGE(0 * BK, 0);
    STAGE(1 * BK, 32768);
    WAIT_VM4();              // tile 0 resident; tile 1 in flight
    RAW_BARRIER();

#pragma unroll 1
    for (int g = 0; g < 21; ++g) {
        const int t = 3 * g;
        STAGE((t + 2) * BK, 65536);  compute(0);      WAIT_VM4(); RAW_BARRIER();
        STAGE((t + 3) * BK, 0);      compute(32768);  WAIT_VM4(); RAW_BARRIER();
        STAGE((t + 4) * BK, 32768);  compute(65536);  WAIT_VM4(); RAW_BARRIER();
    }
    // t = 63 (buf0), stage tile 65 -> buf2
    STAGE(65 * BK, 65536);  compute(0);      WAIT_VM4(); RAW_BARRIER();
    // t = 64 (buf1), nothing left to stage; drain tile 65's loads
    compute(32768);  WAIT_VM0(); RAW_BARRIER();
    // t = 65 (buf2)
    compute(65536);
#undef STAGE

    const float sc = scale[0];
#pragma unroll
    for (int ni = 0; ni < 2; ++ni) {
        const int col = bn0 + wn * 64 + ni * 32 + r31;
        const float bv = bias[col];
#pragma unroll
        for (int mi = 0; mi < 4; ++mi) {
            const int rbase = bm0 + wm * 128 + mi * 32 + 4 * h;
#pragma unroll
            for (int reg = 0; reg < 16; ++reg) {
                const int row = rbase + (reg & 3) + 8 * (reg >> 2);
                C[(size_t)row * N_DIM + col] = sc * acc[mi][ni][reg] + bv;
            }
        }
    }
}

extern "C" void kernel_launch(void* const* d_in, const int* in_sizes, int n_in,
                              void* d_out, int out_size, void* d_ws, size_t ws_size,
                              hipStream_t stream) {
    const int*   A_packed = (const int*)d_in[0];
    const int*   SFA      = (const int*)d_in[1];
    const float* scale    = (const float*)d_in[2];
    const int*   B_packed = (const int*)d_in[3];
    const int*   SFB      = (const int*)d_in[4];
    const float* bias     = (const float*)d_in[5];
    float*       out      = (float*)d_out;

    uint8_t* Abf8 = (uint8_t*)d_ws;
    uint8_t* Bbf8 = Abf8 + (size_t)M_DIM * K_DIM;

    const int nblkA = M_DIM * K_DIM / 16;   // 2,162,688 (8448 blocks of 256)
    const int nblkB = N_DIM * K_DIM / 16;   // 1,081,344 (4224 blocks)
    dequant_all<<<(nblkA + nblkB) / 256, 256, 0, stream>>>(
        A_packed, SFA, Abf8, B_packed, SFB, Bbf8);

    dim3 grid(N_DIM / 256, M_DIM / 256);    // (16, 32) = 512 blocks
    gemm_mx<<<grid, 512, 0, stream>>>(Abf8, Bbf8, scale, bias, out);
}

// Round 3
// 346.185 us; speedup vs baseline: 1.0081x; 1.0019x over previous
//
#include <hip/hip_runtime.h>
#include <stdint.h>

#define M_DIM 8192
#define N_DIM 4096
#define K_DIM 4224
#define BK 64

typedef float f32x16 __attribute__((ext_vector_type(16)));
typedef int   i32x8  __attribute__((ext_vector_type(8)));
typedef int   i32x4  __attribute__((ext_vector_type(4)));

#define RAW_BARRIER()  asm volatile("s_barrier" ::: "memory")
#define WAIT_VM4()     asm volatile("s_waitcnt vmcnt(4)" ::: "memory")
#define WAIT_VM0()     asm volatile("s_waitcnt vmcnt(0)" ::: "memory")

// ---------------------------------------------------------------------------
// fp4(e2m1) nibble + per-16 E8M0 scale -> exact bf8(e5m2), pure VALU.
// ---------------------------------------------------------------------------
__device__ __forceinline__ uint32_t conv4(uint32_t x, uint32_t k1) {
    uint32_t n7   = x & 0x07070707u;
    uint32_t base = __builtin_amdgcn_perm(0x46444240u, 0x3E3C3800u, n7);
    uint32_t nz   = __builtin_amdgcn_perm(0x01010101u, 0x01010100u, n7);
    uint32_t sign = (x & 0x08080808u) << 4;
    return (base + nz * k1 - (nz << 6)) | sign;
}

__global__ __launch_bounds__(256) void dequant_all(
    const int* __restrict__ Ap, const int* __restrict__ SFA, uint8_t* __restrict__ Aout,
    const int* __restrict__ Bp, const int* __restrict__ SFB, uint8_t* __restrict__ Bout)
{
    const int nblkA = M_DIM * K_DIM / 16;
    int i = blockIdx.x * 256 + threadIdx.x;
    const int* p; const int* sf; uint8_t* out; int idx;
    if (i < nblkA) { p = Ap; sf = SFA; out = Aout; idx = i; }
    else           { p = Bp; sf = SFB; out = Bout; idx = i - nblkA; }

    const int4* p4 = (const int4*)p;
    int4 p0 = p4[2 * idx];
    int4 p1 = p4[2 * idx + 1];
    int s4 = (sf[idx] - 127) << 2;
    uint32_t k1 = (uint32_t)(s4 + 64);

    uint32_t o[4];
#pragma unroll
    for (int g = 0; g < 2; ++g) {
        int4 pg = g ? p1 : p0;
        uint32_t w = (uint32_t)(pg.x & 0xFF) | ((uint32_t)(pg.y & 0xFF) << 8) |
                     ((uint32_t)(pg.z & 0xFF) << 16) | ((uint32_t)pg.w << 24);
        uint32_t lr = conv4(w & 0x0F0F0F0Fu, k1);
        uint32_t hr = conv4((w >> 4) & 0x0F0F0F0Fu, k1);
        o[2 * g]     = __builtin_amdgcn_perm(hr, lr, 0x05010400u); // elems 0..3
        o[2 * g + 1] = __builtin_amdgcn_perm(hr, lr, 0x07030602u); // elems 4..7
    }
    *(uint4*)(out + (size_t)idx * 16) = make_uint4(o[0], o[1], o[2], o[3]);
}

// ---------------------------------------------------------------------------
// GEMM via MX-scaled MFMA at unity scale: C = scale*(A.B^T) + bias
// 256x256 tile, 8 waves (2Mx4N), BK=64, bf8 operands.
// - LDS: 4 tile buffers x 32KB = 128 KB; staging depth 3, vmcnt(4)/tile:
//   end of iter t confirms tile t+2 resident, leaves t+3 in flight.
// - Register-pipelined fragments (ping-pong): iter t issues ds_reads for
//   af23(t) and af01/bf01(t+1) BETWEEN its two 4-MFMA clusters, so the LDS
//   banks (96KB/tile reads) and the matrix pipe (1100cy/tile) overlap
//   instead of serializing (round-1 post-mortem: serial -> 2600cy/tile).
// - ONE barrier per tile. XOR-swizzled granules (slot g^((row>>1)&3)).
// - T1 XCD swizzle, T5 setprio around each MFMA cluster.
// ---------------------------------------------------------------------------
__global__ __launch_bounds__(512, 2) void gemm_mx(
    const uint8_t* __restrict__ A, const uint8_t* __restrict__ B,
    const float* __restrict__ scale, const float* __restrict__ bias,
    float* __restrict__ C)
{
    __shared__ uint8_t smem[131072];
    // buf k at offset k*32768: A [256][64] at +0, B [256][64] at +16384

    const int tid  = threadIdx.x;
    const int lane = tid & 63;
    const int w    = tid >> 6;      // 0..7
    const int wm   = w >> 2;        // 0..1 : 128-row band
    const int wn   = w & 3;         // 0..3 : 64-col band
    const int r31  = lane & 31;
    const int h    = lane >> 5;

    // XCD-aware swizzle: 512 blocks total, chunk of 64 consecutive per XCD
    const int lin = blockIdx.y * 16 + blockIdx.x;        // gridDim.x == 16
    const int o   = (lin & 7) * 64 + (lin >> 3);         // bijective (512 % 8 == 0)
    const int bn0 = (o & 15) * 256;
    const int bm0 = (o >> 4) * 256;

    f32x16 acc[4][2];
#pragma unroll
    for (int i = 0; i < 4; ++i)
#pragma unroll
        for (int j = 0; j < 2; ++j)
            acc[i][j] = (f32x16)(0.0f);

    // staging: wave w stages rows [w*32, w*32+32) of A and of B,
    // 2 issues of 16 rows x 64B per matrix (4 global_load_lds per wave per tile).
    const int srow = lane >> 2;
    const int scol = (((lane & 3) ^ ((lane >> 3) & 3)) << 4);
    const uint8_t* Ag = A + (size_t)(bm0 + w * 32 + srow) * K_DIM + scol;
    const uint8_t* Bg = B + (size_t)(bn0 + w * 32 + srow) * K_DIM + scol;
    uint8_t* Asw = smem + w * 2048;
    uint8_t* Bsw = smem + 16384 + w * 2048;

#define STAGE(koff, boff)                                                        \
    do {                                                                         \
        const uint8_t* ag_ = Ag + (koff);                                        \
        const uint8_t* bg_ = Bg + (koff);                                        \
        __builtin_amdgcn_global_load_lds(                                        \
            (const __attribute__((address_space(1))) void*)(ag_),                \
            (__attribute__((address_space(3))) void*)(Asw + (boff)), 16, 0, 0);  \
        __builtin_amdgcn_global_load_lds(                                        \
            (const __attribute__((address_space(1))) void*)(ag_ + (size_t)16 * K_DIM), \
            (__attribute__((address_space(3))) void*)(Asw + (boff) + 1024), 16, 0, 0); \
        __builtin_amdgcn_global_load_lds(                                        \
            (const __attribute__((address_space(1))) void*)(bg_),                \
            (__attribute__((address_space(3))) void*)(Bsw + (boff)), 16, 0, 0);  \
        __builtin_amdgcn_global_load_lds(                                        \
            (const __attribute__((address_space(1))) void*)(bg_ + (size_t)16 * K_DIM), \
            (__attribute__((address_space(3))) void*)(Bsw + (boff) + 1024), 16, 0, 0); \
    } while (0)

    // swizzled, kt-invariant fragment addresses (buf0; bufk = +k*32768)
    const int sx = (r31 >> 1) & 3;
    const uint8_t* pa_lo[4]; const uint8_t* pa_hi[4];
    const uint8_t* pb_lo[2]; const uint8_t* pb_hi[2];
#pragma unroll
    for (int mi = 0; mi < 4; ++mi) {
        const uint8_t* base = smem + (wm * 128 + mi * 32 + r31) * 64;
        pa_lo[mi] = base + (((2 * h)     ^ sx) << 4);
        pa_hi[mi] = base + (((2 * h + 1) ^ sx) << 4);
    }
#pragma unroll
    for (int ni = 0; ni < 2; ++ni) {
        const uint8_t* base = smem + 16384 + (wn * 64 + ni * 32 + r31) * 64;
        pb_lo[ni] = base + (((2 * h)     ^ sx) << 4);
        pb_hi[ni] = base + (((2 * h + 1) ^ sx) << 4);
    }

    i32x8 afX0[2], afX1[2], bfX0[2], bfX1[2], afY[2];

    auto rd = [&](const uint8_t* plo, const uint8_t* phi, int off, i32x8& dst) {
        i32x4 lo = *(const i32x4*)(plo + off);
        i32x4 hi = *(const i32x4*)(phi + off);
        dst = __builtin_shufflevector(lo, hi, 0, 1, 2, 3, 4, 5, 6, 7);
    };
    auto mm = [&](const i32x8& a, const i32x8& b, f32x16& c) {
        c = __builtin_amdgcn_mfma_scale_f32_32x32x64_f8f6f4(
                a, b, c, 1, 1, 0, 0x7F7F7F7F, 0, 0x7F7F7F7F);
    };

// iter t: read af23(t) [buf OB0]; MFMA cluster0 (mi 0,1) on current set;
// read af01/bf01(t+1) [buf OB1] into next set; MFMA cluster1 (mi 2,3).
#define CORE(AC, BC, AN, BN, OB0, OB1)                        \
    rd(pa_lo[2], pa_hi[2], OB0, afY[0]);                      \
    rd(pa_lo[3], pa_hi[3], OB0, afY[1]);                      \
    __builtin_amdgcn_s_setprio(1);                            \
    mm(AC[0], BC[0], acc[0][0]); mm(AC[0], BC[1], acc[0][1]); \
    mm(AC[1], BC[0], acc[1][0]); mm(AC[1], BC[1], acc[1][1]); \
    __builtin_amdgcn_s_setprio(0);                            \
    rd(pa_lo[0], pa_hi[0], OB1, AN[0]);                       \
    rd(pa_lo[1], pa_hi[1], OB1, AN[1]);                       \
    rd(pb_lo[0], pb_hi[0], OB1, BN[0]);                       \
    rd(pb_lo[1], pb_hi[1], OB1, BN[1]);                       \
    __builtin_amdgcn_s_setprio(1);                            \
    mm(afY[0], BC[0], acc[2][0]); mm(afY[0], BC[1], acc[2][1]); \
    mm(afY[1], BC[0], acc[3][0]); mm(afY[1], BC[1], acc[3][1]); \
    __builtin_amdgcn_s_setprio(0);

#define BODY(T, AC, BC, AN, BN, OB0, OB1, OB3)                \
    STAGE(((T) + 3) * BK, OB3);                               \
    CORE(AC, BC, AN, BN, OB0, OB1)                            \
    WAIT_VM4(); RAW_BARRIER();

    // prologue: stage tiles 0,1,2 -> buf0,1,2; confirm 0,1; read frags(0)
    STAGE(0 * BK, 0);
    STAGE(1 * BK, 32768);
    STAGE(2 * BK, 65536);
    WAIT_VM4();              // tiles 0,1 resident; tile 2 in flight
    RAW_BARRIER();
    rd(pa_lo[0], pa_hi[0], 0, afX0[0]);
    rd(pa_lo[1], pa_hi[1], 0, afX0[1]);
    rd(pb_lo[0], pb_hi[0], 0, bfX0[0]);
    rd(pb_lo[1], pb_hi[1], 0, bfX0[1]);

    // main: t = 0..59, unroll 4 (buffer index = t%4, frag parity = t%2)
#pragma unroll 1
    for (int g = 0; g < 15; ++g) {
        const int t = 4 * g;
        BODY(t,     afX0, bfX0, afX1, bfX1, 0,     32768, 98304)
        BODY(t + 1, afX1, bfX1, afX0, bfX0, 32768, 65536, 0)
        BODY(t + 2, afX0, bfX0, afX1, bfX1, 65536, 98304, 32768)
        BODY(t + 3, afX1, bfX1, afX0, bfX0, 98304, 0,     65536)
    }
    // tail: t = 60..65 (stages 63,64,65 then drain)
    BODY(60, afX0, bfX0, afX1, bfX1, 0,     32768, 98304)   // stage 63 -> buf3
    BODY(61, afX1, bfX1, afX0, bfX0, 32768, 65536, 0)       // stage 64 -> buf0
    BODY(62, afX0, bfX0, afX1, bfX1, 65536, 98304, 32768)   // stage 65 -> buf1
    // t=63: no stage; drain tile 65's loads
    CORE(afX1, bfX1, afX0, bfX0, 98304, 0)
    WAIT_VM0(); RAW_BARRIER();
    // t=64: reads tile 65 frags (resident), no barrier needed after
    CORE(afX0, bfX0, afX1, bfX1, 0, 32768)
    // t=65: last tile from buf1
    rd(pa_lo[2], pa_hi[2], 32768, afY[0]);
    rd(pa_lo[3], pa_hi[3], 32768, afY[1]);
    __builtin_amdgcn_s_setprio(1);
    mm(afX1[0], bfX1[0], acc[0][0]); mm(afX1[0], bfX1[1], acc[0][1]);
    mm(afX1[1], bfX1[0], acc[1][0]); mm(afX1[1], bfX1[1], acc[1][1]);
    mm(afY[0],  bfX1[0], acc[2][0]); mm(afY[0],  bfX1[1], acc[2][1]);
    mm(afY[1],  bfX1[0], acc[3][0]); mm(afY[1],  bfX1[1], acc[3][1]);
    __builtin_amdgcn_s_setprio(0);
#undef BODY
#undef CORE
#undef STAGE

    const float sc = scale[0];
#pragma unroll
    for (int ni = 0; ni < 2; ++ni) {
        const int col = bn0 + wn * 64 + ni * 32 + r31;
        const float bv = bias[col];
#pragma unroll
        for (int mi = 0; mi < 4; ++mi) {
            const int rbase = bm0 + wm * 128 + mi * 32 + 4 * h;
#pragma unroll
            for (int reg = 0; reg < 16; ++reg) {
                const int row = rbase + (reg & 3) + 8 * (reg >> 2);
                C[(size_t)row * N_DIM + col] = sc * acc[mi][ni][reg] + bv;
            }
        }
    }
}

extern "C" void kernel_launch(void* const* d_in, const int* in_sizes, int n_in,
                              void* d_out, int out_size, void* d_ws, size_t ws_size,
                              hipStream_t stream) {
    const int*   A_packed = (const int*)d_in[0];
    const int*   SFA      = (const int*)d_in[1];
    const float* scale    = (const float*)d_in[2];
    const int*   B_packed = (const int*)d_in[3];
    const int*   SFB      = (const int*)d_in[4];
    const float* bias     = (const float*)d_in[5];
    float*       out      = (float*)d_out;

    uint8_t* Abf8 = (uint8_t*)d_ws;
    uint8_t* Bbf8 = Abf8 + (size_t)M_DIM * K_DIM;

    const int nblkA = M_DIM * K_DIM / 16;   // 2,162,688 (8448 blocks of 256)
    const int nblkB = N_DIM * K_DIM / 16;   // 1,081,344 (4224 blocks)
    dequant_all<<<(nblkA + nblkB) / 256, 256, 0, stream>>>(
        A_packed, SFA, Abf8, B_packed, SFB, Bbf8);

    dim3 grid(N_DIM / 256, M_DIM / 256);    // (16, 32) = 512 blocks
    gemm_mx<<<grid, 512, 0, stream>>>(Abf8, Bbf8, scale, bias, out);
}

// Round 4
// 342.413 us; speedup vs baseline: 1.0192x; 1.0110x over previous
//
#include <hip/hip_runtime.h>
#include <stdint.h>

#define M_DIM 8192
#define N_DIM 4096
#define K_DIM 4224
#define BK 64

typedef float f32x16 __attribute__((ext_vector_type(16)));
typedef int   i32x8  __attribute__((ext_vector_type(8)));
typedef int   i32x4  __attribute__((ext_vector_type(4)));

#define RAW_BARRIER()  asm volatile("s_barrier" ::: "memory")
#define WAIT_VM4()     asm volatile("s_waitcnt vmcnt(4)" ::: "memory")
#define WAIT_VM0()     asm volatile("s_waitcnt vmcnt(0)" ::: "memory")

// ---------------------------------------------------------------------------
// fp4(e2m1) nibble + per-16 E8M0 scale -> exact bf8(e5m2), pure VALU.
// ---------------------------------------------------------------------------
__device__ __forceinline__ uint32_t conv4(uint32_t x, uint32_t k1) {
    uint32_t n7   = x & 0x07070707u;
    uint32_t base = __builtin_amdgcn_perm(0x46444240u, 0x3E3C3800u, n7);
    uint32_t nz   = __builtin_amdgcn_perm(0x01010101u, 0x01010100u, n7);
    uint32_t sign = (x & 0x08080808u) << 4;
    return (base + nz * k1 - (nz << 6)) | sign;
}

__global__ __launch_bounds__(256) void dequant_all(
    const int* __restrict__ Ap, const int* __restrict__ SFA, uint8_t* __restrict__ Aout,
    const int* __restrict__ Bp, const int* __restrict__ SFB, uint8_t* __restrict__ Bout)
{
    const int nblkA = M_DIM * K_DIM / 16;
    int i = blockIdx.x * 256 + threadIdx.x;
    const int* p; const int* sf; uint8_t* out; int idx;
    if (i < nblkA) { p = Ap; sf = SFA; out = Aout; idx = i; }
    else           { p = Bp; sf = SFB; out = Bout; idx = i - nblkA; }

    const int4* p4 = (const int4*)p;
    int4 p0 = p4[2 * idx];
    int4 p1 = p4[2 * idx + 1];
    int s4 = (sf[idx] - 127) << 2;
    uint32_t k1 = (uint32_t)(s4 + 64);

    uint32_t o[4];
#pragma unroll
    for (int g = 0; g < 2; ++g) {
        int4 pg = g ? p1 : p0;
        uint32_t w = (uint32_t)(pg.x & 0xFF) | ((uint32_t)(pg.y & 0xFF) << 8) |
                     ((uint32_t)(pg.z & 0xFF) << 16) | ((uint32_t)pg.w << 24);
        uint32_t lr = conv4(w & 0x0F0F0F0Fu, k1);
        uint32_t hr = conv4((w >> 4) & 0x0F0F0F0Fu, k1);
        o[2 * g]     = __builtin_amdgcn_perm(hr, lr, 0x05010400u); // elems 0..3
        o[2 * g + 1] = __builtin_amdgcn_perm(hr, lr, 0x07030602u); // elems 4..7
    }
    *(uint4*)(out + (size_t)idx * 16) = make_uint4(o[0], o[1], o[2], o[3]);
}

// ---------------------------------------------------------------------------
// GEMM via MX-scaled MFMA at unity scale: C = scale*(A.B^T) + bias
// 256x256 tile, 8 waves (2Mx4N), BK=64, bf8 operands.
// Round-3 schedule: FULL READ-AHEAD. All 6 fragments of tile t+1 are read
// during iteration t, split around the two MFMA clusters. Post-barrier path
// is STAGE -> cluster0 with ZERO lgkm dependency (operands read a full
// iteration earlier), killing the convoy serialization (r2 post-mortem:
// ~1000 cy/tile with both MFMA and LDS pipes idle).
// Residency proof: stage-ahead-3 + vmcnt(4) at end of EVERY iteration
// confirms tile t+2 before the barrier => reads of t+1 during iteration t
// are globally (all-waves) confirmed one barrier earlier. Prologue vmcnt(4)
// after staging 3 tiles confirms tiles 0 AND 1 for iteration 0's read-ahead.
// End-of-iter vmcnt(4) waits on 2-iteration-old loads => ~free.
// Buffer safety: STAGE(t+3) targets buf (t-1)%4, read during iter t-2,
// two barriers ago. afY needs no ping-pong: cluster1(t) consumes it before
// rd af23(t+1) rewrites it.
// ---------------------------------------------------------------------------
__global__ __launch_bounds__(512, 2) void gemm_mx(
    const uint8_t* __restrict__ A, const uint8_t* __restrict__ B,
    const float* __restrict__ scale, const float* __restrict__ bias,
    float* __restrict__ C)
{
    __shared__ uint8_t smem[131072];
    // buf k at offset k*32768: A [256][64] at +0, B [256][64] at +16384

    const int tid  = threadIdx.x;
    const int lane = tid & 63;
    const int w    = tid >> 6;      // 0..7
    const int wm   = w >> 2;        // 0..1 : 128-row band
    const int wn   = w & 3;         // 0..3 : 64-col band
    const int r31  = lane & 31;
    const int h    = lane >> 5;

    // XCD-aware swizzle: 512 blocks total, chunk of 64 consecutive per XCD
    const int lin = blockIdx.y * 16 + blockIdx.x;        // gridDim.x == 16
    const int o   = (lin & 7) * 64 + (lin >> 3);         // bijective (512 % 8 == 0)
    const int bn0 = (o & 15) * 256;
    const int bm0 = (o >> 4) * 256;

    f32x16 acc[4][2];
#pragma unroll
    for (int i = 0; i < 4; ++i)
#pragma unroll
        for (int j = 0; j < 2; ++j)
            acc[i][j] = (f32x16)(0.0f);

    // staging: wave w stages rows [w*32, w*32+32) of A and of B,
    // 2 issues of 16 rows x 64B per matrix (4 global_load_lds per wave per tile).
    const int srow = lane >> 2;
    const int scol = (((lane & 3) ^ ((lane >> 3) & 3)) << 4);
    const uint8_t* Ag = A + (size_t)(bm0 + w * 32 + srow) * K_DIM + scol;
    const uint8_t* Bg = B + (size_t)(bn0 + w * 32 + srow) * K_DIM + scol;
    uint8_t* Asw = smem + w * 2048;
    uint8_t* Bsw = smem + 16384 + w * 2048;

#define STAGE(koff, boff)                                                        \
    do {                                                                         \
        const uint8_t* ag_ = Ag + (koff);                                        \
        const uint8_t* bg_ = Bg + (koff);                                        \
        __builtin_amdgcn_global_load_lds(                                        \
            (const __attribute__((address_space(1))) void*)(ag_),                \
            (__attribute__((address_space(3))) void*)(Asw + (boff)), 16, 0, 0);  \
        __builtin_amdgcn_global_load_lds(                                        \
            (const __attribute__((address_space(1))) void*)(ag_ + (size_t)16 * K_DIM), \
            (__attribute__((address_space(3))) void*)(Asw + (boff) + 1024), 16, 0, 0); \
        __builtin_amdgcn_global_load_lds(                                        \
            (const __attribute__((address_space(1))) void*)(bg_),                \
            (__attribute__((address_space(3))) void*)(Bsw + (boff)), 16, 0, 0);  \
        __builtin_amdgcn_global_load_lds(                                        \
            (const __attribute__((address_space(1))) void*)(bg_ + (size_t)16 * K_DIM), \
            (__attribute__((address_space(3))) void*)(Bsw + (boff) + 1024), 16, 0, 0); \
    } while (0)

    // swizzled, kt-invariant fragment addresses (buf0; bufk = +k*32768)
    const int sx = (r31 >> 1) & 3;
    const uint8_t* pa_lo[4]; const uint8_t* pa_hi[4];
    const uint8_t* pb_lo[2]; const uint8_t* pb_hi[2];
#pragma unroll
    for (int mi = 0; mi < 4; ++mi) {
        const uint8_t* base = smem + (wm * 128 + mi * 32 + r31) * 64;
        pa_lo[mi] = base + (((2 * h)     ^ sx) << 4);
        pa_hi[mi] = base + (((2 * h + 1) ^ sx) << 4);
    }
#pragma unroll
    for (int ni = 0; ni < 2; ++ni) {
        const uint8_t* base = smem + 16384 + (wn * 64 + ni * 32 + r31) * 64;
        pb_lo[ni] = base + (((2 * h)     ^ sx) << 4);
        pb_hi[ni] = base + (((2 * h + 1) ^ sx) << 4);
    }

    i32x8 afX0[2], afX1[2], bfX0[2], bfX1[2], afY[2];

    auto rd = [&](const uint8_t* plo, const uint8_t* phi, int off, i32x8& dst) {
        i32x4 lo = *(const i32x4*)(plo + off);
        i32x4 hi = *(const i32x4*)(phi + off);
        dst = __builtin_shufflevector(lo, hi, 0, 1, 2, 3, 4, 5, 6, 7);
    };
    auto mm = [&](const i32x8& a, const i32x8& b, f32x16& c) {
        c = __builtin_amdgcn_mfma_scale_f32_32x32x64_f8f6f4(
                a, b, c, 1, 1, 0, 0x7F7F7F7F, 0, 0x7F7F7F7F);
    };

// iteration t (read-ahead): cluster0 on (AC,BC) [read during t-1];
// read af01/bf01(t+1)->AN/BN; cluster1 on (afY,BC); read af23(t+1)->afY.
#define CORE(AC, BC, AN, BN, OBN)                             \
    __builtin_amdgcn_s_setprio(1);                            \
    mm(AC[0], BC[0], acc[0][0]); mm(AC[0], BC[1], acc[0][1]); \
    mm(AC[1], BC[0], acc[1][0]); mm(AC[1], BC[1], acc[1][1]); \
    __builtin_amdgcn_s_setprio(0);                            \
    rd(pa_lo[0], pa_hi[0], OBN, AN[0]);                       \
    rd(pa_lo[1], pa_hi[1], OBN, AN[1]);                       \
    rd(pb_lo[0], pb_hi[0], OBN, BN[0]);                       \
    rd(pb_lo[1], pb_hi[1], OBN, BN[1]);                       \
    __builtin_amdgcn_s_setprio(1);                            \
    mm(afY[0], BC[0], acc[2][0]); mm(afY[0], BC[1], acc[2][1]); \
    mm(afY[1], BC[0], acc[3][0]); mm(afY[1], BC[1], acc[3][1]); \
    __builtin_amdgcn_s_setprio(0);                            \
    rd(pa_lo[2], pa_hi[2], OBN, afY[0]);                      \
    rd(pa_lo[3], pa_hi[3], OBN, afY[1]);

#define BODY(T, AC, BC, AN, BN, OBN, OBS)                     \
    STAGE(((T) + 3) * BK, OBS);                               \
    CORE(AC, BC, AN, BN, OBN)                                 \
    WAIT_VM4(); RAW_BARRIER();

    // prologue: stage tiles 0,1,2 -> buf0,1,2; vmcnt(4) confirms tiles 0 AND 1
    // (globally, via the barrier) so iteration 0 may read-ahead tile 1.
    STAGE(0 * BK, 0);
    STAGE(1 * BK, 32768);
    STAGE(2 * BK, 65536);
    WAIT_VM4();
    RAW_BARRIER();
    // fragments of tile 0 (buf0)
    rd(pa_lo[0], pa_hi[0], 0, afX0[0]);
    rd(pa_lo[1], pa_hi[1], 0, afX0[1]);
    rd(pb_lo[0], pb_hi[0], 0, bfX0[0]);
    rd(pb_lo[1], pb_hi[1], 0, bfX0[1]);
    rd(pa_lo[2], pa_hi[2], 0, afY[0]);
    rd(pa_lo[3], pa_hi[3], 0, afY[1]);

    // main: t = 0..59, unroll 4 (buf of t+1 = (t+1)%4, stage buf = (t+3)%4)
#pragma unroll 1
    for (int g = 0; g < 15; ++g) {
        const int t = 4 * g;
        BODY(t,     afX0, bfX0, afX1, bfX1, 32768, 98304)
        BODY(t + 1, afX1, bfX1, afX0, bfX0, 65536, 0)
        BODY(t + 2, afX0, bfX0, afX1, bfX1, 98304, 32768)
        BODY(t + 3, afX1, bfX1, afX0, bfX0, 0,     65536)
    }
    // tail: t = 60,61,62 still stage (63,64,65)
    BODY(60, afX0, bfX0, afX1, bfX1, 32768, 98304)
    BODY(61, afX1, bfX1, afX0, bfX0, 65536, 0)
    BODY(62, afX0, bfX0, afX1, bfX1, 98304, 32768)
    // t=63: no stage; reads tile 64 (buf0); vmcnt(0) confirms tile 65
    CORE(afX1, bfX1, afX0, bfX0, 0)
    WAIT_VM0(); RAW_BARRIER();
    // t=64: reads tile 65 (buf1); no more LDS writes -> no barrier needed
    CORE(afX0, bfX0, afX1, bfX1, 32768)
    // t=65: clusters only
    __builtin_amdgcn_s_setprio(1);
    mm(afX1[0], bfX1[0], acc[0][0]); mm(afX1[0], bfX1[1], acc[0][1]);
    mm(afX1[1], bfX1[0], acc[1][0]); mm(afX1[1], bfX1[1], acc[1][1]);
    mm(afY[0],  bfX1[0], acc[2][0]); mm(afY[0],  bfX1[1], acc[2][1]);
    mm(afY[1],  bfX1[0], acc[3][0]); mm(afY[1],  bfX1[1], acc[3][1]);
    __builtin_amdgcn_s_setprio(0);
#undef BODY
#undef CORE
#undef STAGE

    const float sc = scale[0];
#pragma unroll
    for (int ni = 0; ni < 2; ++ni) {
        const int col = bn0 + wn * 64 + ni * 32 + r31;
        const float bv = bias[col];
#pragma unroll
        for (int mi = 0; mi < 4; ++mi) {
            const int rbase = bm0 + wm * 128 + mi * 32 + 4 * h;
#pragma unroll
            for (int reg = 0; reg < 16; ++reg) {
                const int row = rbase + (reg & 3) + 8 * (reg >> 2);
                C[(size_t)row * N_DIM + col] = sc * acc[mi][ni][reg] + bv;
            }
        }
    }
}

extern "C" void kernel_launch(void* const* d_in, const int* in_sizes, int n_in,
                              void* d_out, int out_size, void* d_ws, size_t ws_size,
                              hipStream_t stream) {
    const int*   A_packed = (const int*)d_in[0];
    const int*   SFA      = (const int*)d_in[1];
    const float* scale    = (const float*)d_in[2];
    const int*   B_packed = (const int*)d_in[3];
    const int*   SFB      = (const int*)d_in[4];
    const float* bias     = (const float*)d_in[5];
    float*       out      = (float*)d_out;

    uint8_t* Abf8 = (uint8_t*)d_ws;
    uint8_t* Bbf8 = Abf8 + (size_t)M_DIM * K_DIM;

    const int nblkA = M_DIM * K_DIM / 16;   // 2,162,688 (8448 blocks of 256)
    const int nblkB = N_DIM * K_DIM / 16;   // 1,081,344 (4224 blocks)
    dequant_all<<<(nblkA + nblkB) / 256, 256, 0, stream>>>(
        A_packed, SFA, Abf8, B_packed, SFB, Bbf8);

    dim3 grid(N_DIM / 256, M_DIM / 256);    // (16, 32) = 512 blocks
    gemm_mx<<<grid, 512, 0, stream>>>(Abf8, Bbf8, scale, bias, out);
}